// Round 13
// baseline (250.786 us; speedup 1.0000x reference)
//
#include <hip/hip_runtime.h>
#include <hip/hip_bf16.h>

// Problem constants (from reference)
constexpr int N  = 50000;   // nodes
constexpr int E  = 800000;  // edges
constexpr int D0 = 64;      // IN_DIM
constexpr int D1 = 128;     // HID_DIM
constexpr int CAP = 64;     // per-node neighbor capacity (Poisson(16) tail)

constexpr int NPART = 8;                       // XCD count
constexpr int PSZ   = (N + NPART - 1) / NPART; // 6250 nodes per partition
constexpr int BPP   = 128;                     // blocks per partition

typedef __attribute__((ext_vector_type(8))) short short8;   // 8 bf16 = 4 VGPR
typedef __attribute__((ext_vector_type(4))) float f32x4;

__device__ __forceinline__ unsigned short bf16bits(float f) {
    __hip_bfloat16 hb = __float2bfloat16(f);
    return *reinterpret_cast<unsigned short*>(&hb);
}

// accumulate 8 bf16 (packed in uint4) into 8 f32 accumulators
__device__ __forceinline__ void acc8(float* a, const uint4 r) {
    union { unsigned u; float f; } c;
    c.u = r.x << 16;         a[0] += c.f;
    c.u = r.x & 0xffff0000u; a[1] += c.f;
    c.u = r.y << 16;         a[2] += c.f;
    c.u = r.y & 0xffff0000u; a[3] += c.f;
    c.u = r.z << 16;         a[4] += c.f;
    c.u = r.z & 0xffff0000u; a[5] += c.f;
    c.u = r.w << 16;         a[6] += c.f;
    c.u = r.w & 0xffff0000u; a[7] += c.f;
}

// ---------------------------------------------------------------------------
// Fused prep: zero cnt, convert x -> bf16, pack weights -> bf16.
// All jobs indexed off one grid (disjoint arrays; overlapping i ok).
// ---------------------------------------------------------------------------
__global__ __launch_bounds__(256)
void k_prep(const float* __restrict__ x, unsigned short* __restrict__ xb,
            const float* __restrict__ W1l, const float* __restrict__ W1r,
            const float* __restrict__ W2l, const float* __restrict__ W2r,
            unsigned short* __restrict__ W1cat, unsigned short* __restrict__ W2cat,
            int* __restrict__ cnt) {
    int i = blockIdx.x * blockDim.x + threadIdx.x;
    if (i < N / 4) ((int4*)cnt)[i] = make_int4(0, 0, 0, 0);
    if (i < 128 * 128) {
        int o = i >> 7, k = i & 127;
        float v = (k < 64) ? W1l[o * 64 + k] : W1r[o * 64 + (k - 64)];
        W1cat[i] = bf16bits(v);
    }
    if (i < 128 * 256) {
        int o = i >> 8, k = i & 255;
        float v = (k < 128) ? W2l[o * 128 + k] : W2r[o * 128 + (k - 128)];
        W2cat[i] = bf16bits(v);
    }
    if (i < N * D0 / 8) {
        const float4 v0 = *(const float4*)&x[(size_t)i * 8];
        const float4 v1 = *(const float4*)&x[(size_t)i * 8 + 4];
        float f[8] = {v0.x, v0.y, v0.z, v0.w, v1.x, v1.y, v1.z, v1.w};
        unsigned short u[8];
        #pragma unroll
        for (int j = 0; j < 8; ++j) u[j] = bf16bits(f[j]);
        *(short8*)&xb[(size_t)i * 8] = *(short8*)u;
    }
}

// ---------------------------------------------------------------------------
// XCD-partitioned binning (round-10 structure, measured best; ushort bin):
// blocks with blockIdx%8==p handle dst range [p*PSZ,(p+1)*PSZ) exclusively,
// so cnt atomics and bin stores stay in one XCD's L2 and lines accumulate
// ~deg entries before write-back. Edge list re-read 8x but L3-resident.
// Mapping is a locality heuristic only (G16).
// ---------------------------------------------------------------------------
__global__ __launch_bounds__(256)
void k_bin(const int* __restrict__ src, const int* __restrict__ dst,
           int* __restrict__ cnt, unsigned short* __restrict__ bin) {
    const int p     = blockIdx.x & (NPART - 1);   // partition = XCD guess
    const int local = blockIdx.x >> 3;            // 0..BPP-1
    const int lo = p * PSZ;
    const int hi = min(N, lo + PSZ);

    for (int i = local * 256 + threadIdx.x; i < E / 4; i += BPP * 256) {
        const int e0 = i * 4;
        int4 d = *(const int4*)&dst[e0];
        int4 s = *(const int4*)&src[e0];
        if (d.x >= lo && d.x < hi) {
            int pos = atomicAdd(&cnt[d.x], 1);
            if (pos < CAP) bin[(size_t)d.x * CAP + pos] = (unsigned short)s.x;
        }
        if (d.y >= lo && d.y < hi) {
            int pos = atomicAdd(&cnt[d.y], 1);
            if (pos < CAP) bin[(size_t)d.y * CAP + pos] = (unsigned short)s.y;
        }
        if (d.z >= lo && d.z < hi) {
            int pos = atomicAdd(&cnt[d.z], 1);
            if (pos < CAP) bin[(size_t)d.z * CAP + pos] = (unsigned short)s.z;
        }
        if (d.w >= lo && d.w < hi) {
            int pos = atomicAdd(&cnt[d.w], 1);
            if (pos < CAP) bin[(size_t)d.w * CAP + pos] = (unsigned short)s.w;
        }
    }
}

// ---------------------------------------------------------------------------
// Gather + mean over bf16 features: mean[n,:] = sum_nbr(xin) / max(deg,1)
// Neighbor lists at fixed stride CAP (ushort ids). Sub-wave groups of DIN/8
// lanes, 16B (short8) per lane; 8 neighbor rows in flight (round 12 had 4;
// gather2 ran at ~4.6 TB/s effective, well under L3 BW -> latency-limited).
// ---------------------------------------------------------------------------
template<int DIN>
__global__ __launch_bounds__(256, 8)
void k_gather(const unsigned short* __restrict__ xin,  // bf16 [N][DIN]
              const int* __restrict__ cnt,
              const unsigned short* __restrict__ bin,  // [N][CAP]
              unsigned short* __restrict__ mean) {     // bf16 [N][DIN]
    constexpr int GRPSZ = DIN / 8;      // 8 (D0) or 16 (D1)
    constexpr int GPB   = 256 / GRPSZ;  // 32 or 16
    const int tid      = threadIdx.x;
    const int sub      = tid & (GRPSZ - 1);
    const int gloc     = tid / GRPSZ;
    const int lane     = tid & 63;
    const int lanebase = (lane / GRPSZ) * GRPSZ;
    const int g0   = blockIdx.x * GPB + gloc;
    const int gstr = gridDim.x * GPB;

    for (int n = g0; n < N; n += gstr) {
        const int deg  = cnt[n];
        const int degc = min(deg, CAP);
        const size_t base = (size_t)n * CAP;

        float a[8] = {0.f, 0.f, 0.f, 0.f, 0.f, 0.f, 0.f, 0.f};

        for (int b = 0; b < degc; b += GRPSZ) {
            int nb = (b + sub < degc) ? (int)bin[base + b + sub] : 0;
            const int c = min(GRPSZ, degc - b);
            int j = 0;
            for (; j + 8 <= c; j += 8) {
                int s0 = __shfl(nb, lanebase + j + 0);
                int s1 = __shfl(nb, lanebase + j + 1);
                int s2 = __shfl(nb, lanebase + j + 2);
                int s3 = __shfl(nb, lanebase + j + 3);
                int s4 = __shfl(nb, lanebase + j + 4);
                int s5 = __shfl(nb, lanebase + j + 5);
                int s6 = __shfl(nb, lanebase + j + 6);
                int s7 = __shfl(nb, lanebase + j + 7);
                uint4 r0 = *(const uint4*)&xin[(size_t)s0 * DIN + sub * 8];
                uint4 r1 = *(const uint4*)&xin[(size_t)s1 * DIN + sub * 8];
                uint4 r2 = *(const uint4*)&xin[(size_t)s2 * DIN + sub * 8];
                uint4 r3 = *(const uint4*)&xin[(size_t)s3 * DIN + sub * 8];
                uint4 r4 = *(const uint4*)&xin[(size_t)s4 * DIN + sub * 8];
                uint4 r5 = *(const uint4*)&xin[(size_t)s5 * DIN + sub * 8];
                uint4 r6 = *(const uint4*)&xin[(size_t)s6 * DIN + sub * 8];
                uint4 r7 = *(const uint4*)&xin[(size_t)s7 * DIN + sub * 8];
                acc8(a, r0); acc8(a, r1); acc8(a, r2); acc8(a, r3);
                acc8(a, r4); acc8(a, r5); acc8(a, r6); acc8(a, r7);
            }
            for (; j + 4 <= c; j += 4) {
                int s0 = __shfl(nb, lanebase + j + 0);
                int s1 = __shfl(nb, lanebase + j + 1);
                int s2 = __shfl(nb, lanebase + j + 2);
                int s3 = __shfl(nb, lanebase + j + 3);
                uint4 r0 = *(const uint4*)&xin[(size_t)s0 * DIN + sub * 8];
                uint4 r1 = *(const uint4*)&xin[(size_t)s1 * DIN + sub * 8];
                uint4 r2 = *(const uint4*)&xin[(size_t)s2 * DIN + sub * 8];
                uint4 r3 = *(const uint4*)&xin[(size_t)s3 * DIN + sub * 8];
                acc8(a, r0); acc8(a, r1); acc8(a, r2); acc8(a, r3);
            }
            for (; j < c; ++j) {
                int s = __shfl(nb, lanebase + j);
                uint4 r = *(const uint4*)&xin[(size_t)s * DIN + sub * 8];
                acc8(a, r);
            }
        }

        const float invd = 1.0f / fmaxf((float)deg, 1.0f);
        unsigned short u[8];
        #pragma unroll
        for (int q = 0; q < 8; ++q) u[q] = bf16bits(a[q] * invd);
        *(short8*)&mean[(size_t)n * DIN + sub * 8] = *(short8*)u;
    }
}

// ---------------------------------------------------------------------------
// MFMA dense: out[n,:] = relu?( [mean[n]|xin[n]] @ Wcat^T + bias )
// K = 2*DIN. 64 nodes/block, 4 waves; each wave: 16 nodes x 128 outs via 8
// accumulator fragments of mfma_f32_16x16x32_bf16. A staged in LDS (bf16
// short8 copy), row padded +8. B from global Wcat (L1-hot).
// Fragment layouts per m89/m91.
// ---------------------------------------------------------------------------
template<int DIN, bool RELU, bool OUT_BF16>
__global__ __launch_bounds__(256)
void k_mdense(const unsigned short* __restrict__ mean,
              const unsigned short* __restrict__ xin,
              const unsigned short* __restrict__ Wcat,  // [128][K] bf16
              const float* __restrict__ bias,
              void* __restrict__ out,
              int n_nodes) {
    constexpr int K  = 2 * DIN;       // 128 or 256
    constexpr int KP = K + 8;         // padded row (bf16 units)
    __shared__ unsigned short A[64 * KP];

    const int tid   = threadIdx.x;
    const int nbase = blockIdx.x * 64;

    // ---- Stage A = [mean | xin] (bf16 copy) ----
    constexpr int CPR   = K / 8;
    constexpr int TOTAL = 64 * CPR;
    for (int c = tid; c < TOTAL; c += 256) {
        int row  = c / CPR;
        int col8 = (c - row * CPR) * 8;
        int n    = nbase + row;
        short8 v = (short8)0;
        if (n < n_nodes) {
            const unsigned short* srcp = (col8 < DIN)
                ? &mean[(size_t)n * DIN + col8]
                : &xin[(size_t)n * DIN + (col8 - DIN)];
            v = *(const short8*)srcp;
        }
        *(short8*)&A[row * KP + col8] = v;
    }
    __syncthreads();

    // ---- MFMA ----
    const int lane = tid & 63;
    const int wv   = tid >> 6;
    const int l15  = lane & 15;
    const int kseg = lane >> 4;

    f32x4 acc[8];
    #pragma unroll
    for (int ot = 0; ot < 8; ++ot) acc[ot] = (f32x4){0.f, 0.f, 0.f, 0.f};

    #pragma unroll
    for (int kk = 0; kk < K / 32; ++kk) {
        short8 a = *(const short8*)&A[(wv * 16 + l15) * KP + kk * 32 + kseg * 8];
        #pragma unroll
        for (int ot = 0; ot < 8; ++ot) {
            short8 b = *(const short8*)&Wcat[(size_t)(ot * 16 + l15) * K + kk * 32 + kseg * 8];
            acc[ot] = __builtin_amdgcn_mfma_f32_16x16x32_bf16(a, b, acc[ot], 0, 0, 0);
        }
    }

    // ---- Epilogue ----
    #pragma unroll
    for (int ot = 0; ot < 8; ++ot) {
        const int o  = ot * 16 + l15;
        const float bv = bias[o];
        #pragma unroll
        for (int i = 0; i < 4; ++i) {
            int n = nbase + wv * 16 + kseg * 4 + i;
            if (n < n_nodes) {
                float v = acc[ot][i] + bv;
                if constexpr (RELU) v = fmaxf(v, 0.0f);
                if constexpr (OUT_BF16) {
                    ((unsigned short*)out)[(size_t)n * 128 + o] = bf16bits(v);
                } else {
                    ((float*)out)[(size_t)n * 128 + o] = v;
                }
            }
        }
    }
}

// ---------------------------------------------------------------------------
extern "C" void kernel_launch(void* const* d_in, const int* in_sizes, int n_in,
                              void* d_out, int out_size, void* d_ws, size_t ws_size,
                              hipStream_t stream) {
    const float* x   = (const float*)d_in[0];
    const int*   ei  = (const int*)d_in[1];   // [2, E] int32
    const float* W1l = (const float*)d_in[2];
    const float* W1r = (const float*)d_in[3];
    const float* b1  = (const float*)d_in[4];
    const float* W2l = (const float*)d_in[5];
    const float* W2r = (const float*)d_in[6];
    const float* b2  = (const float*)d_in[7];
    float*       out = (float*)d_out;

    const int* src = ei;       // edge_index[0]
    const int* dst = ei + E;   // edge_index[1]

    // Workspace (16B-aligned bump allocator), ~24 MB total
    char* p = (char*)d_ws;
    auto alloc = [&](size_t bytes) -> char* {
        char* r = p; p += (bytes + 15) & ~(size_t)15; return r;
    };
    int*            cnt   = (int*)alloc(N * sizeof(int));
    unsigned short* bin   = (unsigned short*)alloc((size_t)N * CAP * 2);  // 6.4 MB
    unsigned short* xb    = (unsigned short*)alloc((size_t)N * D0 * 2);
    unsigned short* h     = (unsigned short*)alloc((size_t)N * D1 * 2);
    unsigned short* mean  = (unsigned short*)alloc((size_t)N * D1 * 2);
    unsigned short* W1cat = (unsigned short*)alloc(128 * 128 * 2);
    unsigned short* W2cat = (unsigned short*)alloc(128 * 256 * 2);

    const int nblk_d = (N + 63) / 64;  // 782

    // ---- fused prep: zero cnt, cvt x, pack weights ----
    k_prep<<<(N * D0 / 8 + 255) / 256, 256, 0, stream>>>(
        x, xb, W1l, W1r, W2l, W2r, W1cat, W2cat, cnt);

    // ---- adjacency build: one XCD-partitioned atomic pass ----
    k_bin<<<NPART * BPP, 256, 0, stream>>>(src, dst, cnt, bin);

    // ---- Layer 1: xb -> h (ReLU, bf16) ----
    k_gather<D0><<<2048, 256, 0, stream>>>(xb, cnt, bin, mean);
    k_mdense<D0, /*RELU=*/true, /*OUT_BF16=*/true>
        <<<nblk_d, 256, 0, stream>>>(mean, xb, W1cat, b1, h, N);

    // ---- Layer 2: h -> out (f32) ----
    k_gather<D1><<<2048, 256, 0, stream>>>(h, cnt, bin, mean);
    k_mdense<D1, /*RELU=*/false, /*OUT_BF16=*/false>
        <<<nblk_d, 256, 0, stream>>>(mean, h, W2cat, b2, out, N);
}

// Round 14
// 168.233 us; speedup vs baseline: 1.4907x; 1.4907x over previous
//
#include <hip/hip_runtime.h>
#include <hip/hip_bf16.h>

// Problem constants (from reference)
constexpr int N  = 50000;   // nodes
constexpr int E  = 800000;  // edges
constexpr int D0 = 64;      // IN_DIM
constexpr int D1 = 128;     // HID_DIM
constexpr int CAP = 64;     // per-node neighbor capacity (Poisson(16) tail)

constexpr int NPART = 8;                       // XCD count
constexpr int PSZ   = (N + NPART - 1) / NPART; // 6250 nodes per partition
constexpr int BPP   = 128;                     // blocks per partition

typedef __attribute__((ext_vector_type(8))) short short8;   // 8 bf16 = 4 VGPR
typedef __attribute__((ext_vector_type(4))) float f32x4;

__device__ __forceinline__ unsigned short bf16bits(float f) {
    __hip_bfloat16 hb = __float2bfloat16(f);
    return *reinterpret_cast<unsigned short*>(&hb);
}

// accumulate 8 bf16 (packed in uint4) into 8 f32 accumulators
__device__ __forceinline__ void acc8(float* a, const uint4 r) {
    union { unsigned u; float f; } c;
    c.u = r.x << 16;         a[0] += c.f;
    c.u = r.x & 0xffff0000u; a[1] += c.f;
    c.u = r.y << 16;         a[2] += c.f;
    c.u = r.y & 0xffff0000u; a[3] += c.f;
    c.u = r.z << 16;         a[4] += c.f;
    c.u = r.z & 0xffff0000u; a[5] += c.f;
    c.u = r.w << 16;         a[6] += c.f;
    c.u = r.w & 0xffff0000u; a[7] += c.f;
}

// ---------------------------------------------------------------------------
// Fused prep: zero cnt, convert x -> bf16, pack weights -> bf16.
// ---------------------------------------------------------------------------
__global__ __launch_bounds__(256)
void k_prep(const float* __restrict__ x, unsigned short* __restrict__ xb,
            const float* __restrict__ W1l, const float* __restrict__ W1r,
            const float* __restrict__ W2l, const float* __restrict__ W2r,
            unsigned short* __restrict__ W1cat, unsigned short* __restrict__ W2cat,
            int* __restrict__ cnt) {
    int i = blockIdx.x * blockDim.x + threadIdx.x;
    if (i < N / 4) ((int4*)cnt)[i] = make_int4(0, 0, 0, 0);
    if (i < 128 * 128) {
        int o = i >> 7, k = i & 127;
        float v = (k < 64) ? W1l[o * 64 + k] : W1r[o * 64 + (k - 64)];
        W1cat[i] = bf16bits(v);
    }
    if (i < 128 * 256) {
        int o = i >> 8, k = i & 255;
        float v = (k < 128) ? W2l[o * 128 + k] : W2r[o * 128 + (k - 128)];
        W2cat[i] = bf16bits(v);
    }
    if (i < N * D0 / 8) {
        const float4 v0 = *(const float4*)&x[(size_t)i * 8];
        const float4 v1 = *(const float4*)&x[(size_t)i * 8 + 4];
        float f[8] = {v0.x, v0.y, v0.z, v0.w, v1.x, v1.y, v1.z, v1.w};
        unsigned short u[8];
        #pragma unroll
        for (int j = 0; j < 8; ++j) u[j] = bf16bits(f[j]);
        *(short8*)&xb[(size_t)i * 8] = *(short8*)u;
    }
}

// ---------------------------------------------------------------------------
// XCD-partitioned binning (round-10 structure, measured best; ushort bin):
// blocks with blockIdx%8==p handle dst range [p*PSZ,(p+1)*PSZ) exclusively,
// so cnt atomics and bin stores stay in one XCD's L2. Edge list re-read 8x
// but L3-resident. Mapping is a locality heuristic only (G16).
// ---------------------------------------------------------------------------
__global__ __launch_bounds__(256)
void k_bin(const int* __restrict__ src, const int* __restrict__ dst,
           int* __restrict__ cnt, unsigned short* __restrict__ bin) {
    const int p     = blockIdx.x & (NPART - 1);   // partition = XCD guess
    const int local = blockIdx.x >> 3;            // 0..BPP-1
    const int lo = p * PSZ;
    const int hi = min(N, lo + PSZ);

    for (int i = local * 256 + threadIdx.x; i < E / 4; i += BPP * 256) {
        const int e0 = i * 4;
        int4 d = *(const int4*)&dst[e0];
        int4 s = *(const int4*)&src[e0];
        if (d.x >= lo && d.x < hi) {
            int pos = atomicAdd(&cnt[d.x], 1);
            if (pos < CAP) bin[(size_t)d.x * CAP + pos] = (unsigned short)s.x;
        }
        if (d.y >= lo && d.y < hi) {
            int pos = atomicAdd(&cnt[d.y], 1);
            if (pos < CAP) bin[(size_t)d.y * CAP + pos] = (unsigned short)s.y;
        }
        if (d.z >= lo && d.z < hi) {
            int pos = atomicAdd(&cnt[d.z], 1);
            if (pos < CAP) bin[(size_t)d.z * CAP + pos] = (unsigned short)s.z;
        }
        if (d.w >= lo && d.w < hi) {
            int pos = atomicAdd(&cnt[d.w], 1);
            if (pos < CAP) bin[(size_t)d.w * CAP + pos] = (unsigned short)s.w;
        }
    }
}

// ---------------------------------------------------------------------------
// Gather + mean over bf16 features: mean[n,:] = sum_nbr(xin) / max(deg,1)
// REVERTED to the measured-best 4-deep MLP (round 13's 8-deep forced the
// compiler to serialize under the 64-VGPR cap of launch_bounds(256,8):
// VGPR dropped 44->32 and gather time doubled. depth x payload must fit
// the occupancy-capped register budget).
// ---------------------------------------------------------------------------
template<int DIN>
__global__ __launch_bounds__(256, 8)
void k_gather(const unsigned short* __restrict__ xin,  // bf16 [N][DIN]
              const int* __restrict__ cnt,
              const unsigned short* __restrict__ bin,  // [N][CAP]
              unsigned short* __restrict__ mean) {     // bf16 [N][DIN]
    constexpr int GRPSZ = DIN / 8;      // 8 (D0) or 16 (D1)
    constexpr int GPB   = 256 / GRPSZ;  // 32 or 16
    const int tid      = threadIdx.x;
    const int sub      = tid & (GRPSZ - 1);
    const int gloc     = tid / GRPSZ;
    const int lane     = tid & 63;
    const int lanebase = (lane / GRPSZ) * GRPSZ;
    const int g0   = blockIdx.x * GPB + gloc;
    const int gstr = gridDim.x * GPB;

    for (int n = g0; n < N; n += gstr) {
        const int deg  = cnt[n];
        const int degc = min(deg, CAP);
        const size_t base = (size_t)n * CAP;

        float a[8] = {0.f, 0.f, 0.f, 0.f, 0.f, 0.f, 0.f, 0.f};

        for (int b = 0; b < degc; b += GRPSZ) {
            int nb = (b + sub < degc) ? (int)bin[base + b + sub] : 0;
            const int c = min(GRPSZ, degc - b);
            int j = 0;
            for (; j + 4 <= c; j += 4) {
                int s0 = __shfl(nb, lanebase + j + 0);
                int s1 = __shfl(nb, lanebase + j + 1);
                int s2 = __shfl(nb, lanebase + j + 2);
                int s3 = __shfl(nb, lanebase + j + 3);
                uint4 r0 = *(const uint4*)&xin[(size_t)s0 * DIN + sub * 8];
                uint4 r1 = *(const uint4*)&xin[(size_t)s1 * DIN + sub * 8];
                uint4 r2 = *(const uint4*)&xin[(size_t)s2 * DIN + sub * 8];
                uint4 r3 = *(const uint4*)&xin[(size_t)s3 * DIN + sub * 8];
                acc8(a, r0); acc8(a, r1); acc8(a, r2); acc8(a, r3);
            }
            for (; j < c; ++j) {
                int s = __shfl(nb, lanebase + j);
                uint4 r = *(const uint4*)&xin[(size_t)s * DIN + sub * 8];
                acc8(a, r);
            }
        }

        const float invd = 1.0f / fmaxf((float)deg, 1.0f);
        unsigned short u[8];
        #pragma unroll
        for (int q = 0; q < 8; ++q) u[q] = bf16bits(a[q] * invd);
        *(short8*)&mean[(size_t)n * DIN + sub * 8] = *(short8*)u;
    }
}

// ---------------------------------------------------------------------------
// MFMA dense: out[n,:] = relu?( [mean[n]|xin[n]] @ Wcat^T + bias )
// K = 2*DIN. 64 nodes/block, 4 waves; each wave: 16 nodes x 128 outs via 8
// accumulator fragments of mfma_f32_16x16x32_bf16. A staged in LDS (bf16
// short8 copy), row padded +8. B from global Wcat (L1-hot).
// Fragment layouts per m89/m91.
// ---------------------------------------------------------------------------
template<int DIN, bool RELU, bool OUT_BF16>
__global__ __launch_bounds__(256)
void k_mdense(const unsigned short* __restrict__ mean,
              const unsigned short* __restrict__ xin,
              const unsigned short* __restrict__ Wcat,  // [128][K] bf16
              const float* __restrict__ bias,
              void* __restrict__ out,
              int n_nodes) {
    constexpr int K  = 2 * DIN;       // 128 or 256
    constexpr int KP = K + 8;         // padded row (bf16 units)
    __shared__ unsigned short A[64 * KP];

    const int tid   = threadIdx.x;
    const int nbase = blockIdx.x * 64;

    // ---- Stage A = [mean | xin] (bf16 copy) ----
    constexpr int CPR   = K / 8;
    constexpr int TOTAL = 64 * CPR;
    for (int c = tid; c < TOTAL; c += 256) {
        int row  = c / CPR;
        int col8 = (c - row * CPR) * 8;
        int n    = nbase + row;
        short8 v = (short8)0;
        if (n < n_nodes) {
            const unsigned short* srcp = (col8 < DIN)
                ? &mean[(size_t)n * DIN + col8]
                : &xin[(size_t)n * DIN + (col8 - DIN)];
            v = *(const short8*)srcp;
        }
        *(short8*)&A[row * KP + col8] = v;
    }
    __syncthreads();

    // ---- MFMA ----
    const int lane = tid & 63;
    const int wv   = tid >> 6;
    const int l15  = lane & 15;
    const int kseg = lane >> 4;

    f32x4 acc[8];
    #pragma unroll
    for (int ot = 0; ot < 8; ++ot) acc[ot] = (f32x4){0.f, 0.f, 0.f, 0.f};

    #pragma unroll
    for (int kk = 0; kk < K / 32; ++kk) {
        short8 a = *(const short8*)&A[(wv * 16 + l15) * KP + kk * 32 + kseg * 8];
        #pragma unroll
        for (int ot = 0; ot < 8; ++ot) {
            short8 b = *(const short8*)&Wcat[(size_t)(ot * 16 + l15) * K + kk * 32 + kseg * 8];
            acc[ot] = __builtin_amdgcn_mfma_f32_16x16x32_bf16(a, b, acc[ot], 0, 0, 0);
        }
    }

    // ---- Epilogue ----
    #pragma unroll
    for (int ot = 0; ot < 8; ++ot) {
        const int o  = ot * 16 + l15;
        const float bv = bias[o];
        #pragma unroll
        for (int i = 0; i < 4; ++i) {
            int n = nbase + wv * 16 + kseg * 4 + i;
            if (n < n_nodes) {
                float v = acc[ot][i] + bv;
                if constexpr (RELU) v = fmaxf(v, 0.0f);
                if constexpr (OUT_BF16) {
                    ((unsigned short*)out)[(size_t)n * 128 + o] = bf16bits(v);
                } else {
                    ((float*)out)[(size_t)n * 128 + o] = v;
                }
            }
        }
    }
}

// ---------------------------------------------------------------------------
extern "C" void kernel_launch(void* const* d_in, const int* in_sizes, int n_in,
                              void* d_out, int out_size, void* d_ws, size_t ws_size,
                              hipStream_t stream) {
    const float* x   = (const float*)d_in[0];
    const int*   ei  = (const int*)d_in[1];   // [2, E] int32
    const float* W1l = (const float*)d_in[2];
    const float* W1r = (const float*)d_in[3];
    const float* b1  = (const float*)d_in[4];
    const float* W2l = (const float*)d_in[5];
    const float* W2r = (const float*)d_in[6];
    const float* b2  = (const float*)d_in[7];
    float*       out = (float*)d_out;

    const int* src = ei;       // edge_index[0]
    const int* dst = ei + E;   // edge_index[1]

    // Workspace (16B-aligned bump allocator), ~24 MB total
    char* p = (char*)d_ws;
    auto alloc = [&](size_t bytes) -> char* {
        char* r = p; p += (bytes + 15) & ~(size_t)15; return r;
    };
    int*            cnt   = (int*)alloc(N * sizeof(int));
    unsigned short* bin   = (unsigned short*)alloc((size_t)N * CAP * 2);  // 6.4 MB
    unsigned short* xb    = (unsigned short*)alloc((size_t)N * D0 * 2);
    unsigned short* h     = (unsigned short*)alloc((size_t)N * D1 * 2);
    unsigned short* mean  = (unsigned short*)alloc((size_t)N * D1 * 2);
    unsigned short* W1cat = (unsigned short*)alloc(128 * 128 * 2);
    unsigned short* W2cat = (unsigned short*)alloc(128 * 256 * 2);

    const int nblk_d = (N + 63) / 64;  // 782

    // ---- fused prep: zero cnt, cvt x, pack weights ----
    k_prep<<<(N * D0 / 8 + 255) / 256, 256, 0, stream>>>(
        x, xb, W1l, W1r, W2l, W2r, W1cat, W2cat, cnt);

    // ---- adjacency build: one XCD-partitioned atomic pass ----
    k_bin<<<NPART * BPP, 256, 0, stream>>>(src, dst, cnt, bin);

    // ---- Layer 1: xb -> h (ReLU, bf16) ----
    k_gather<D0><<<2048, 256, 0, stream>>>(xb, cnt, bin, mean);
    k_mdense<D0, /*RELU=*/true, /*OUT_BF16=*/true>
        <<<nblk_d, 256, 0, stream>>>(mean, xb, W1cat, b1, h, N);

    // ---- Layer 2: h -> out (f32) ----
    k_gather<D1><<<2048, 256, 0, stream>>>(h, cnt, bin, mean);
    k_mdense<D1, /*RELU=*/false, /*OUT_BF16=*/false>
        <<<nblk_d, 256, 0, stream>>>(mean, h, W2cat, b2, out, N);
}

// Round 15
// 158.646 us; speedup vs baseline: 1.5808x; 1.0604x over previous
//
#include <hip/hip_runtime.h>
#include <hip/hip_bf16.h>

// Problem constants (from reference)
constexpr int N  = 50000;   // nodes
constexpr int E  = 800000;  // edges
constexpr int D0 = 64;      // IN_DIM
constexpr int D1 = 128;     // HID_DIM
constexpr int CAP = 64;     // per-node neighbor capacity (Poisson(16) tail)

constexpr int NPART = 8;                       // XCD count
constexpr int PSZ   = (N + NPART - 1) / NPART; // 6250 nodes per partition
constexpr int BPP   = 128;                     // blocks per partition

typedef __attribute__((ext_vector_type(8))) short short8;   // 8 bf16 = 4 VGPR
typedef __attribute__((ext_vector_type(4))) float f32x4;

__device__ __forceinline__ unsigned short bf16bits(float f) {
    __hip_bfloat16 hb = __float2bfloat16(f);
    return *reinterpret_cast<unsigned short*>(&hb);
}

// accumulate 8 bf16 (packed in uint4) into 8 f32 accumulators
__device__ __forceinline__ void acc8(float* a, const uint4 r) {
    union { unsigned u; float f; } c;
    c.u = r.x << 16;         a[0] += c.f;
    c.u = r.x & 0xffff0000u; a[1] += c.f;
    c.u = r.y << 16;         a[2] += c.f;
    c.u = r.y & 0xffff0000u; a[3] += c.f;
    c.u = r.z << 16;         a[4] += c.f;
    c.u = r.z & 0xffff0000u; a[5] += c.f;
    c.u = r.w << 16;         a[6] += c.f;
    c.u = r.w & 0xffff0000u; a[7] += c.f;
}

// ---------------------------------------------------------------------------
// Fused prep: zero cnt, convert x -> bf16, pack weights -> bf16.
// ---------------------------------------------------------------------------
__global__ __launch_bounds__(256)
void k_prep(const float* __restrict__ x, unsigned short* __restrict__ xb,
            const float* __restrict__ W1l, const float* __restrict__ W1r,
            const float* __restrict__ W2l, const float* __restrict__ W2r,
            unsigned short* __restrict__ W1cat, unsigned short* __restrict__ W2cat,
            int* __restrict__ cnt) {
    int i = blockIdx.x * blockDim.x + threadIdx.x;
    if (i < N / 4) ((int4*)cnt)[i] = make_int4(0, 0, 0, 0);
    if (i < 128 * 128) {
        int o = i >> 7, k = i & 127;
        float v = (k < 64) ? W1l[o * 64 + k] : W1r[o * 64 + (k - 64)];
        W1cat[i] = bf16bits(v);
    }
    if (i < 128 * 256) {
        int o = i >> 8, k = i & 255;
        float v = (k < 128) ? W2l[o * 128 + k] : W2r[o * 128 + (k - 128)];
        W2cat[i] = bf16bits(v);
    }
    if (i < N * D0 / 8) {
        const float4 v0 = *(const float4*)&x[(size_t)i * 8];
        const float4 v1 = *(const float4*)&x[(size_t)i * 8 + 4];
        float f[8] = {v0.x, v0.y, v0.z, v0.w, v1.x, v1.y, v1.z, v1.w};
        unsigned short u[8];
        #pragma unroll
        for (int j = 0; j < 8; ++j) u[j] = bf16bits(f[j]);
        *(short8*)&xb[(size_t)i * 8] = *(short8*)u;
    }
}

// ---------------------------------------------------------------------------
// XCD-partitioned binning (measured best): blocks with blockIdx%8==p handle
// dst range [p*PSZ,(p+1)*PSZ) exclusively, so cnt atomics and bin stores stay
// in one XCD's L2. Edge list re-read 8x but L3-resident. Mapping is a
// locality heuristic only (G16).
// ---------------------------------------------------------------------------
__global__ __launch_bounds__(256)
void k_bin(const int* __restrict__ src, const int* __restrict__ dst,
           int* __restrict__ cnt, unsigned short* __restrict__ bin) {
    const int p     = blockIdx.x & (NPART - 1);   // partition = XCD guess
    const int local = blockIdx.x >> 3;            // 0..BPP-1
    const int lo = p * PSZ;
    const int hi = min(N, lo + PSZ);

    for (int i = local * 256 + threadIdx.x; i < E / 4; i += BPP * 256) {
        const int e0 = i * 4;
        int4 d = *(const int4*)&dst[e0];
        int4 s = *(const int4*)&src[e0];
        if (d.x >= lo && d.x < hi) {
            int pos = atomicAdd(&cnt[d.x], 1);
            if (pos < CAP) bin[(size_t)d.x * CAP + pos] = (unsigned short)s.x;
        }
        if (d.y >= lo && d.y < hi) {
            int pos = atomicAdd(&cnt[d.y], 1);
            if (pos < CAP) bin[(size_t)d.y * CAP + pos] = (unsigned short)s.y;
        }
        if (d.z >= lo && d.z < hi) {
            int pos = atomicAdd(&cnt[d.z], 1);
            if (pos < CAP) bin[(size_t)d.z * CAP + pos] = (unsigned short)s.z;
        }
        if (d.w >= lo && d.w < hi) {
            int pos = atomicAdd(&cnt[d.w], 1);
            if (pos < CAP) bin[(size_t)d.w * CAP + pos] = (unsigned short)s.w;
        }
    }
}

// ---------------------------------------------------------------------------
// Fused SAGE layer: gather-mean (phase A) + MFMA dense (phase B), one kernel.
// Rationale: the 6-node serial graph had ~8-10us gap per dependency edge --
// fusing gather into dense removes 2 nodes and the 25.6MB mean round-trip.
// Phase A: 4-deep-MLP gather (the measured-best inner loop; 8-deep
//   serialized under the VGPR cap, round 13) writes bf16 mean directly into
//   the LDS A-tile's left half; root features copied into the right half.
// Phase B: mfma_f32_16x16x32_bf16, 4 waves x (16 nodes x 128 outs), B
//   fragments from L1-hot Wcat. Fragment layouts per m89/m91.
// LDS: layer1 17.4KB (8 blocks/CU, thread-capped), layer2 33.8KB (4/CU --
//   acceptable: gather phase is BW-bound at ~4.5TB/s, not occupancy-bound,
//   per round-5/6 evidence).
// ---------------------------------------------------------------------------
template<int DIN, bool RELU, bool OUT_BF16>
__global__ __launch_bounds__(256)
void k_layer(const unsigned short* __restrict__ xin,  // bf16 [N][DIN]
             const int* __restrict__ cnt,
             const unsigned short* __restrict__ bin,  // [N][CAP] ushort ids
             const unsigned short* __restrict__ Wcat, // [128][2*DIN] bf16
             const float* __restrict__ bias,
             void* __restrict__ out,
             int n_nodes) {
    constexpr int K  = 2 * DIN;       // 128 or 256
    constexpr int KP = K + 8;         // padded row (bf16 units)
    __shared__ unsigned short A[64 * KP];

    const int tid   = threadIdx.x;
    const int nbase = blockIdx.x * 64;

    // ---- Phase A1: root copy into right half of A ----
    constexpr int CPR = DIN / 8;      // 8-elem chunks per row (root half)
    for (int c = tid; c < 64 * CPR; c += 256) {
        int row  = c / CPR;
        int col8 = (c - row * CPR) * 8;
        int n    = nbase + row;
        short8 v = (short8)0;
        if (n < n_nodes) v = *(const short8*)&xin[(size_t)n * DIN + col8];
        *(short8*)&A[row * KP + DIN + col8] = v;
    }

    // ---- Phase A2: gather-mean into left half of A ----
    {
        constexpr int GRPSZ = DIN / 8;      // 8 (D0) or 16 (D1)
        constexpr int NGRP  = 256 / GRPSZ;  // 32 or 16 groups per block
        constexpr int NPG   = 64 / NGRP;    // 2 or 4 nodes per group
        const int sub      = tid & (GRPSZ - 1);
        const int gloc     = tid / GRPSZ;
        const int lane     = tid & 63;
        const int lanebase = (lane / GRPSZ) * GRPSZ;

        #pragma unroll
        for (int i = 0; i < NPG; ++i) {
            const int row = gloc * NPG + i;
            const int n   = nbase + row;

            float a[8] = {0.f, 0.f, 0.f, 0.f, 0.f, 0.f, 0.f, 0.f};
            int deg = 0;
            if (n < n_nodes) {
                deg = cnt[n];
                const int degc = min(deg, CAP);
                const size_t base = (size_t)n * CAP;
                for (int b = 0; b < degc; b += GRPSZ) {
                    int nb = (b + sub < degc) ? (int)bin[base + b + sub] : 0;
                    const int c = min(GRPSZ, degc - b);
                    int j = 0;
                    for (; j + 4 <= c; j += 4) {
                        int s0 = __shfl(nb, lanebase + j + 0);
                        int s1 = __shfl(nb, lanebase + j + 1);
                        int s2 = __shfl(nb, lanebase + j + 2);
                        int s3 = __shfl(nb, lanebase + j + 3);
                        uint4 r0 = *(const uint4*)&xin[(size_t)s0 * DIN + sub * 8];
                        uint4 r1 = *(const uint4*)&xin[(size_t)s1 * DIN + sub * 8];
                        uint4 r2 = *(const uint4*)&xin[(size_t)s2 * DIN + sub * 8];
                        uint4 r3 = *(const uint4*)&xin[(size_t)s3 * DIN + sub * 8];
                        acc8(a, r0); acc8(a, r1); acc8(a, r2); acc8(a, r3);
                    }
                    for (; j < c; ++j) {
                        int s = __shfl(nb, lanebase + j);
                        uint4 r = *(const uint4*)&xin[(size_t)s * DIN + sub * 8];
                        acc8(a, r);
                    }
                }
            }

            const float invd = 1.0f / fmaxf((float)deg, 1.0f);
            unsigned short u[8];
            #pragma unroll
            for (int q = 0; q < 8; ++q) u[q] = bf16bits(a[q] * invd);
            *(short8*)&A[row * KP + sub * 8] = *(short8*)u;
        }
    }
    __syncthreads();

    // ---- Phase B: MFMA ----
    const int lane = tid & 63;
    const int wv   = tid >> 6;
    const int l15  = lane & 15;
    const int kseg = lane >> 4;

    f32x4 acc[8];
    #pragma unroll
    for (int ot = 0; ot < 8; ++ot) acc[ot] = (f32x4){0.f, 0.f, 0.f, 0.f};

    #pragma unroll
    for (int kk = 0; kk < K / 32; ++kk) {
        short8 a = *(const short8*)&A[(wv * 16 + l15) * KP + kk * 32 + kseg * 8];
        #pragma unroll
        for (int ot = 0; ot < 8; ++ot) {
            short8 b = *(const short8*)&Wcat[(size_t)(ot * 16 + l15) * K + kk * 32 + kseg * 8];
            acc[ot] = __builtin_amdgcn_mfma_f32_16x16x32_bf16(a, b, acc[ot], 0, 0, 0);
        }
    }

    // ---- Epilogue ----
    #pragma unroll
    for (int ot = 0; ot < 8; ++ot) {
        const int o  = ot * 16 + l15;
        const float bv = bias[o];
        #pragma unroll
        for (int i = 0; i < 4; ++i) {
            int n = nbase + wv * 16 + kseg * 4 + i;
            if (n < n_nodes) {
                float v = acc[ot][i] + bv;
                if constexpr (RELU) v = fmaxf(v, 0.0f);
                if constexpr (OUT_BF16) {
                    ((unsigned short*)out)[(size_t)n * 128 + o] = bf16bits(v);
                } else {
                    ((float*)out)[(size_t)n * 128 + o] = v;
                }
            }
        }
    }
}

// ---------------------------------------------------------------------------
extern "C" void kernel_launch(void* const* d_in, const int* in_sizes, int n_in,
                              void* d_out, int out_size, void* d_ws, size_t ws_size,
                              hipStream_t stream) {
    const float* x   = (const float*)d_in[0];
    const int*   ei  = (const int*)d_in[1];   // [2, E] int32
    const float* W1l = (const float*)d_in[2];
    const float* W1r = (const float*)d_in[3];
    const float* b1  = (const float*)d_in[4];
    const float* W2l = (const float*)d_in[5];
    const float* W2r = (const float*)d_in[6];
    const float* b2  = (const float*)d_in[7];
    float*       out = (float*)d_out;

    const int* src = ei;       // edge_index[0]
    const int* dst = ei + E;   // edge_index[1]

    // Workspace (16B-aligned bump allocator), ~19 MB total
    char* p = (char*)d_ws;
    auto alloc = [&](size_t bytes) -> char* {
        char* r = p; p += (bytes + 15) & ~(size_t)15; return r;
    };
    int*            cnt   = (int*)alloc(N * sizeof(int));
    unsigned short* bin   = (unsigned short*)alloc((size_t)N * CAP * 2);  // 6.4 MB
    unsigned short* xb    = (unsigned short*)alloc((size_t)N * D0 * 2);
    unsigned short* h     = (unsigned short*)alloc((size_t)N * D1 * 2);
    unsigned short* W1cat = (unsigned short*)alloc(128 * 128 * 2);
    unsigned short* W2cat = (unsigned short*)alloc(128 * 256 * 2);

    const int nblk = (N + 63) / 64;  // 782

    // ---- fused prep: zero cnt, cvt x, pack weights ----
    k_prep<<<(N * D0 / 8 + 255) / 256, 256, 0, stream>>>(
        x, xb, W1l, W1r, W2l, W2r, W1cat, W2cat, cnt);

    // ---- adjacency build: one XCD-partitioned atomic pass ----
    k_bin<<<NPART * BPP, 256, 0, stream>>>(src, dst, cnt, bin);

    // ---- Layer 1 (fused gather+dense): xb -> h (ReLU, bf16) ----
    k_layer<D0, /*RELU=*/true, /*OUT_BF16=*/true>
        <<<nblk, 256, 0, stream>>>(xb, cnt, bin, W1cat, b1, h, N);

    // ---- Layer 2 (fused gather+dense): h -> out (f32) ----
    k_layer<D1, /*RELU=*/false, /*OUT_BF16=*/false>
        <<<nblk, 256, 0, stream>>>(h, cnt, bin, W2cat, b2, out, N);
}

// Round 16
// 158.410 us; speedup vs baseline: 1.5831x; 1.0015x over previous
//
#include <hip/hip_runtime.h>
#include <hip/hip_bf16.h>

// Problem constants (from reference)
constexpr int N  = 50000;   // nodes
constexpr int E  = 800000;  // edges
constexpr int D0 = 64;      // IN_DIM
constexpr int D1 = 128;     // HID_DIM
constexpr int CAP = 64;     // per-node neighbor capacity (Poisson(16) tail)

constexpr int NPART = 8;                       // XCD count
constexpr int PSZ   = (N + NPART - 1) / NPART; // 6250 nodes per partition
constexpr int BPP   = 128;                     // blocks per partition

typedef __attribute__((ext_vector_type(8))) short short8;   // 8 bf16 = 4 VGPR
typedef __attribute__((ext_vector_type(4))) float f32x4;

__device__ __forceinline__ unsigned short bf16bits(float f) {
    __hip_bfloat16 hb = __float2bfloat16(f);
    return *reinterpret_cast<unsigned short*>(&hb);
}

// accumulate 8 bf16 (packed in uint4) into 8 f32 accumulators
__device__ __forceinline__ void acc8(float* a, const uint4 r) {
    union { unsigned u; float f; } c;
    c.u = r.x << 16;         a[0] += c.f;
    c.u = r.x & 0xffff0000u; a[1] += c.f;
    c.u = r.y << 16;         a[2] += c.f;
    c.u = r.y & 0xffff0000u; a[3] += c.f;
    c.u = r.z << 16;         a[4] += c.f;
    c.u = r.z & 0xffff0000u; a[5] += c.f;
    c.u = r.w << 16;         a[6] += c.f;
    c.u = r.w & 0xffff0000u; a[7] += c.f;
}

// ---------------------------------------------------------------------------
// Fused prep: zero cnt, convert x -> bf16, pack weights -> bf16.
// ---------------------------------------------------------------------------
__global__ __launch_bounds__(256)
void k_prep(const float* __restrict__ x, unsigned short* __restrict__ xb,
            const float* __restrict__ W1l, const float* __restrict__ W1r,
            const float* __restrict__ W2l, const float* __restrict__ W2r,
            unsigned short* __restrict__ W1cat, unsigned short* __restrict__ W2cat,
            int* __restrict__ cnt) {
    int i = blockIdx.x * blockDim.x + threadIdx.x;
    if (i < N / 4) ((int4*)cnt)[i] = make_int4(0, 0, 0, 0);
    if (i < 128 * 128) {
        int o = i >> 7, k = i & 127;
        float v = (k < 64) ? W1l[o * 64 + k] : W1r[o * 64 + (k - 64)];
        W1cat[i] = bf16bits(v);
    }
    if (i < 128 * 256) {
        int o = i >> 8, k = i & 255;
        float v = (k < 128) ? W2l[o * 128 + k] : W2r[o * 128 + (k - 128)];
        W2cat[i] = bf16bits(v);
    }
    if (i < N * D0 / 8) {
        const float4 v0 = *(const float4*)&x[(size_t)i * 8];
        const float4 v1 = *(const float4*)&x[(size_t)i * 8 + 4];
        float f[8] = {v0.x, v0.y, v0.z, v0.w, v1.x, v1.y, v1.z, v1.w};
        unsigned short u[8];
        #pragma unroll
        for (int j = 0; j < 8; ++j) u[j] = bf16bits(f[j]);
        *(short8*)&xb[(size_t)i * 8] = *(short8*)u;
    }
}

// ---------------------------------------------------------------------------
// XCD-partitioned binning (measured best): blocks with blockIdx%8==p handle
// dst range [p*PSZ,(p+1)*PSZ) exclusively, so cnt atomics and bin stores stay
// in one XCD's L2. Edge list re-read 8x but L3-resident. Mapping is a
// locality heuristic only (G16).
// ---------------------------------------------------------------------------
__global__ __launch_bounds__(256)
void k_bin(const int* __restrict__ src, const int* __restrict__ dst,
           int* __restrict__ cnt, unsigned short* __restrict__ bin) {
    const int p     = blockIdx.x & (NPART - 1);   // partition = XCD guess
    const int local = blockIdx.x >> 3;            // 0..BPP-1
    const int lo = p * PSZ;
    const int hi = min(N, lo + PSZ);

    for (int i = local * 256 + threadIdx.x; i < E / 4; i += BPP * 256) {
        const int e0 = i * 4;
        int4 d = *(const int4*)&dst[e0];
        int4 s = *(const int4*)&src[e0];
        if (d.x >= lo && d.x < hi) {
            int pos = atomicAdd(&cnt[d.x], 1);
            if (pos < CAP) bin[(size_t)d.x * CAP + pos] = (unsigned short)s.x;
        }
        if (d.y >= lo && d.y < hi) {
            int pos = atomicAdd(&cnt[d.y], 1);
            if (pos < CAP) bin[(size_t)d.y * CAP + pos] = (unsigned short)s.y;
        }
        if (d.z >= lo && d.z < hi) {
            int pos = atomicAdd(&cnt[d.z], 1);
            if (pos < CAP) bin[(size_t)d.z * CAP + pos] = (unsigned short)s.z;
        }
        if (d.w >= lo && d.w < hi) {
            int pos = atomicAdd(&cnt[d.w], 1);
            if (pos < CAP) bin[(size_t)d.w * CAP + pos] = (unsigned short)s.w;
        }
    }
}

// ---------------------------------------------------------------------------
// Fused SAGE layer: gather-mean (phase A) + MFMA dense (phase B).
// NT = nodes per block. Round 15 ran NT=64 for both layers; layer 2's
// 33.8KB LDS capped residency at 4 blocks/CU (Occupancy 27.6%) and the
// latency-bound gather phase inherited that. NT=32 for layer 2 halves LDS
// (16.9KB -> 8 blocks/CU, thread-capped) to double gather-phase waves.
// Phase B tiling: 4 waves = (NT/16) row-tiles x (64/(NT/4)) col-groups;
//   each wave: 16 nodes x (128/NCG) outs. Fragment layouts per m89/m91.
// ---------------------------------------------------------------------------
template<int DIN, int NT, bool RELU, bool OUT_BF16>
__global__ __launch_bounds__(256)
void k_layer(const unsigned short* __restrict__ xin,  // bf16 [N][DIN]
             const int* __restrict__ cnt,
             const unsigned short* __restrict__ bin,  // [N][CAP] ushort ids
             const unsigned short* __restrict__ Wcat, // [128][2*DIN] bf16
             const float* __restrict__ bias,
             void* __restrict__ out,
             int n_nodes) {
    constexpr int K  = 2 * DIN;       // 128 or 256
    constexpr int KP = K + 8;         // padded row (bf16 units)
    __shared__ unsigned short A[NT * KP];

    const int tid   = threadIdx.x;
    const int nbase = blockIdx.x * NT;

    // ---- Phase A1: root copy into right half of A ----
    constexpr int CPR = DIN / 8;      // 8-elem chunks per row (root half)
    for (int c = tid; c < NT * CPR; c += 256) {
        int row  = c / CPR;
        int col8 = (c - row * CPR) * 8;
        int n    = nbase + row;
        short8 v = (short8)0;
        if (n < n_nodes) v = *(const short8*)&xin[(size_t)n * DIN + col8];
        *(short8*)&A[row * KP + DIN + col8] = v;
    }

    // ---- Phase A2: gather-mean into left half of A ----
    {
        constexpr int GRPSZ = DIN / 8;      // 8 (D0) or 16 (D1)
        constexpr int NGRP  = 256 / GRPSZ;  // 32 or 16 groups per block
        constexpr int NPG   = NT / NGRP;    // nodes per group
        const int sub      = tid & (GRPSZ - 1);
        const int gloc     = tid / GRPSZ;
        const int lane     = tid & 63;
        const int lanebase = (lane / GRPSZ) * GRPSZ;

        #pragma unroll
        for (int i = 0; i < NPG; ++i) {
            const int row = gloc * NPG + i;
            const int n   = nbase + row;

            float a[8] = {0.f, 0.f, 0.f, 0.f, 0.f, 0.f, 0.f, 0.f};
            int deg = 0;
            if (n < n_nodes) {
                deg = cnt[n];
                const int degc = min(deg, CAP);
                const size_t base = (size_t)n * CAP;
                for (int b = 0; b < degc; b += GRPSZ) {
                    int nb = (b + sub < degc) ? (int)bin[base + b + sub] : 0;
                    const int c = min(GRPSZ, degc - b);
                    int j = 0;
                    for (; j + 4 <= c; j += 4) {
                        int s0 = __shfl(nb, lanebase + j + 0);
                        int s1 = __shfl(nb, lanebase + j + 1);
                        int s2 = __shfl(nb, lanebase + j + 2);
                        int s3 = __shfl(nb, lanebase + j + 3);
                        uint4 r0 = *(const uint4*)&xin[(size_t)s0 * DIN + sub * 8];
                        uint4 r1 = *(const uint4*)&xin[(size_t)s1 * DIN + sub * 8];
                        uint4 r2 = *(const uint4*)&xin[(size_t)s2 * DIN + sub * 8];
                        uint4 r3 = *(const uint4*)&xin[(size_t)s3 * DIN + sub * 8];
                        acc8(a, r0); acc8(a, r1); acc8(a, r2); acc8(a, r3);
                    }
                    for (; j < c; ++j) {
                        int s = __shfl(nb, lanebase + j);
                        uint4 r = *(const uint4*)&xin[(size_t)s * DIN + sub * 8];
                        acc8(a, r);
                    }
                }
            }

            const float invd = 1.0f / fmaxf((float)deg, 1.0f);
            unsigned short u[8];
            #pragma unroll
            for (int q = 0; q < 8; ++q) u[q] = bf16bits(a[q] * invd);
            *(short8*)&A[row * KP + sub * 8] = *(short8*)u;
        }
    }
    __syncthreads();

    // ---- Phase B: MFMA ----
    constexpr int WR  = NT / 16;   // row-tiles (4 or 2)
    constexpr int NCG = 4 / WR;    // col-groups (1 or 2)
    constexpr int OT  = 8 / NCG;   // out-tiles per wave (8 or 4)
    const int lane = tid & 63;
    const int wv   = tid >> 6;
    const int wr   = wv % WR;      // row-tile of this wave
    const int wc   = wv / WR;      // col-group of this wave
    const int l15  = lane & 15;
    const int kseg = lane >> 4;

    f32x4 acc[OT];
    #pragma unroll
    for (int ot = 0; ot < OT; ++ot) acc[ot] = (f32x4){0.f, 0.f, 0.f, 0.f};

    #pragma unroll
    for (int kk = 0; kk < K / 32; ++kk) {
        short8 a = *(const short8*)&A[(wr * 16 + l15) * KP + kk * 32 + kseg * 8];
        #pragma unroll
        for (int ot = 0; ot < OT; ++ot) {
            const int o16 = wc * OT + ot;   // 16-wide output tile index
            short8 b = *(const short8*)&Wcat[(size_t)(o16 * 16 + l15) * K + kk * 32 + kseg * 8];
            acc[ot] = __builtin_amdgcn_mfma_f32_16x16x32_bf16(a, b, acc[ot], 0, 0, 0);
        }
    }

    // ---- Epilogue ----
    #pragma unroll
    for (int ot = 0; ot < OT; ++ot) {
        const int o  = (wc * OT + ot) * 16 + l15;
        const float bv = bias[o];
        #pragma unroll
        for (int i = 0; i < 4; ++i) {
            int n = nbase + wr * 16 + kseg * 4 + i;
            if (n < n_nodes) {
                float v = acc[ot][i] + bv;
                if constexpr (RELU) v = fmaxf(v, 0.0f);
                if constexpr (OUT_BF16) {
                    ((unsigned short*)out)[(size_t)n * 128 + o] = bf16bits(v);
                } else {
                    ((float*)out)[(size_t)n * 128 + o] = v;
                }
            }
        }
    }
}

// ---------------------------------------------------------------------------
extern "C" void kernel_launch(void* const* d_in, const int* in_sizes, int n_in,
                              void* d_out, int out_size, void* d_ws, size_t ws_size,
                              hipStream_t stream) {
    const float* x   = (const float*)d_in[0];
    const int*   ei  = (const int*)d_in[1];   // [2, E] int32
    const float* W1l = (const float*)d_in[2];
    const float* W1r = (const float*)d_in[3];
    const float* b1  = (const float*)d_in[4];
    const float* W2l = (const float*)d_in[5];
    const float* W2r = (const float*)d_in[6];
    const float* b2  = (const float*)d_in[7];
    float*       out = (float*)d_out;

    const int* src = ei;       // edge_index[0]
    const int* dst = ei + E;   // edge_index[1]

    // Workspace (16B-aligned bump allocator), ~19 MB total
    char* p = (char*)d_ws;
    auto alloc = [&](size_t bytes) -> char* {
        char* r = p; p += (bytes + 15) & ~(size_t)15; return r;
    };
    int*            cnt   = (int*)alloc(N * sizeof(int));
    unsigned short* bin   = (unsigned short*)alloc((size_t)N * CAP * 2);  // 6.4 MB
    unsigned short* xb    = (unsigned short*)alloc((size_t)N * D0 * 2);
    unsigned short* h     = (unsigned short*)alloc((size_t)N * D1 * 2);
    unsigned short* W1cat = (unsigned short*)alloc(128 * 128 * 2);
    unsigned short* W2cat = (unsigned short*)alloc(128 * 256 * 2);

    // ---- fused prep: zero cnt, cvt x, pack weights ----
    k_prep<<<(N * D0 / 8 + 255) / 256, 256, 0, stream>>>(
        x, xb, W1l, W1r, W2l, W2r, W1cat, W2cat, cnt);

    // ---- adjacency build: one XCD-partitioned atomic pass ----
    k_bin<<<NPART * BPP, 256, 0, stream>>>(src, dst, cnt, bin);

    // ---- Layer 1 (fused, NT=64): xb -> h (ReLU, bf16) ----
    k_layer<D0, 64, /*RELU=*/true, /*OUT_BF16=*/true>
        <<<(N + 63) / 64, 256, 0, stream>>>(xb, cnt, bin, W1cat, b1, h, N);

    // ---- Layer 2 (fused, NT=32 -> 16.9KB LDS, 8 blocks/CU): h -> out ----
    k_layer<D1, 32, /*RELU=*/false, /*OUT_BF16=*/false>
        <<<(N + 31) / 32, 256, 0, stream>>>(h, cnt, bin, W2cat, b2, out, N);
}